// Round 3
// baseline (687.323 us; speedup 1.0000x reference)
//
#include <hip/hip_runtime.h>
#include <math.h>

#define BLOCK 256
#define IPB 2   // images per block

union SmemU {
    float img[IPB][3][32][36];   // 27648 B, row stride 36 (pad: kills bank conflicts)
    struct {                      // live only after conv1 is done with img
        float p2[IPB][400];
        float a1[IPB][120];
        float a2[IPB][84];
    } f;
};

__device__ __forceinline__ void load_w25(const float* __restrict__ wp, float (&w)[25]) {
#pragma unroll
    for (int q = 0; q < 6; q++) {
        float4 v = *(const float4*)(wp + 4*q);
        w[4*q+0] = v.x; w[4*q+1] = v.y; w[4*q+2] = v.z; w[4*q+3] = v.w;
    }
    w[24] = wp[24];
}

// Fused per-image LeNet: conv1+pool -> conv2+pool -> fc1 -> fc2 -> fc3(emb)
__global__ __launch_bounds__(BLOCK, 2) void lenet_fused(
    const float* __restrict__ x,
    const float* __restrict__ c1w, const float* __restrict__ c1b,
    const float* __restrict__ c2w, const float* __restrict__ c2b,
    const float* __restrict__ f1w, const float* __restrict__ f1b,
    const float* __restrict__ f2w, const float* __restrict__ f2b,
    const float* __restrict__ f3w, const float* __restrict__ f3b,
    float* __restrict__ emb_out)
{
    __shared__ __align__(16) SmemU u;
    __shared__ __align__(16) float c1w_s[6][3][28];     // padded rows, 16B-aligned
    __shared__ __align__(16) float c2w_s[16][6][28];
    __shared__ __align__(16) float p1_s[IPB][6][14][18]; // row stride 18 (pad)
    __shared__ float c1b_s[6];
    __shared__ float c2b_s[16];

    const int t = threadIdx.x;

    // ---- stage conv weights into padded LDS ----
    float* c1p = &c1w_s[0][0][0];
    for (int idx = t; idx < 450; idx += BLOCK) { int k = idx % 25, r = idx / 25; c1p[r*28 + k] = c1w[idx]; }
    float* c2p = &c2w_s[0][0][0];
    for (int idx = t; idx < 2400; idx += BLOCK) { int k = idx % 25, r = idx / 25; c2p[r*28 + k] = c2w[idx]; }
    if (t < 6)  c1b_s[t] = c1b[t];
    if (t < 16) c2b_s[t] = c2b[t];

    // ---- stage images (coalesced float4 read, padded-row write) ----
    // IPB images x 3 channels x 32 rows = 192 rows; 8 float4 per source row,
    // 9 float4 slots per padded dest row.
    const float4* xin = (const float4*)(x + (size_t)blockIdx.x * (IPB*3072));
    {
        float4* ip = (float4*)&u.img[0][0][0][0];
        for (int idx = t; idx < 192*8; idx += BLOCK) {
            int row = idx >> 3, q = idx & 7;
            ip[row*9 + q] = xin[idx];
        }
    }
    __syncthreads();

    // ---- conv1 + relu + pool2 : [3,32,32] -> [6,14,14] ----
    // work item = (i, c, py, pp): 2 pooled outputs (conv patch 2 rows x 4 cols)
    for (int item = t; item < IPB*6*14*7; item += BLOCK) {
        int pp = item % 7;
        int rem = item / 7;
        int py = rem % 14; rem /= 14;
        int c = rem % 6;
        int i = rem / 6;
        const int y0 = py*2, x0 = pp*4;
        float acc[2][4] = {{0.f,0.f,0.f,0.f},{0.f,0.f,0.f,0.f}};
#pragma unroll
        for (int ci = 0; ci < 3; ci++) {
            float w[25];
            load_w25(&c1w_s[c][ci][0], w);
#pragma unroll
            for (int iy = 0; iy < 6; iy++) {
                const float* rp = &u.img[i][ci][y0+iy][x0];
                float4 va = *(const float4*)rp;
                float4 vb = *(const float4*)(rp+4);
                float r8[8] = {va.x,va.y,va.z,va.w,vb.x,vb.y,vb.z,vb.w};
#pragma unroll
                for (int cr = 0; cr < 2; cr++) {
                    const int ky = iy - cr;
                    if (ky >= 0 && ky < 5) {
#pragma unroll
                        for (int kx = 0; kx < 5; kx++)
#pragma unroll
                            for (int cx = 0; cx < 4; cx++)
                                acc[cr][cx] += w[ky*5+kx] * r8[kx+cx];
                    }
                }
            }
        }
        const float b = c1b_s[c];
        float m0 = fmaxf(fmaxf(acc[0][0], acc[0][1]), fmaxf(acc[1][0], acc[1][1]));
        float m1 = fmaxf(fmaxf(acc[0][2], acc[0][3]), fmaxf(acc[1][2], acc[1][3]));
        p1_s[i][c][py][pp*2+0] = fmaxf(m0 + b, 0.f);
        p1_s[i][c][py][pp*2+1] = fmaxf(m1 + b, 0.f);
    }
    __syncthreads();

    // ---- conv2 + relu + pool2 : [6,14,14] -> [16,5,5] ----
    for (int item = t; item < IPB*16*25; item += BLOCK) {
        int px = item % 5;
        int rem = item / 5;
        int py = rem % 5; rem /= 5;
        int co = rem % 16;
        int i = rem / 16;
        const int y0 = py*2, x0 = px*2;
        float acc[2][2] = {{0.f,0.f},{0.f,0.f}};
#pragma unroll
        for (int ci = 0; ci < 6; ci++) {
            float w[25];
            load_w25(&c2w_s[co][ci][0], w);
#pragma unroll
            for (int iy = 0; iy < 6; iy++) {
                const float* rp = &p1_s[i][ci][y0+iy][x0];
                float2 va = *(const float2*)rp;
                float2 vb = *(const float2*)(rp+2);
                float2 vc = *(const float2*)(rp+4);
                float r6[6] = {va.x,va.y,vb.x,vb.y,vc.x,vc.y};
#pragma unroll
                for (int cr = 0; cr < 2; cr++) {
                    const int ky = iy - cr;
                    if (ky >= 0 && ky < 5) {
#pragma unroll
                        for (int kx = 0; kx < 5; kx++)
#pragma unroll
                            for (int cx = 0; cx < 2; cx++)
                                acc[cr][cx] += w[ky*5+kx] * r6[kx+cx];
                    }
                }
            }
        }
        const float b = c2b_s[co];
        float mv = fmaxf(fmaxf(acc[0][0], acc[0][1]), fmaxf(acc[1][0], acc[1][1]));
        u.f.p2[i][co*25 + py*5 + px] = fmaxf(mv + b, 0.f);   // flatten = c*25+y*5+x
    }
    __syncthreads();

    // ---- fc1: 400 -> 120, relu ----
    if (t < IPB*120) {
        int o = t % 120, i = t / 120;
        float acc = f1b[o];
        const float4* wr = (const float4*)(f1w + o*400);
        const float4* ar = (const float4*)&u.f.p2[i][0];
#pragma unroll 5
        for (int k = 0; k < 100; k++) {
            float4 w4 = wr[k], a4 = ar[k];
            acc += w4.x*a4.x + w4.y*a4.y + w4.z*a4.z + w4.w*a4.w;
        }
        u.f.a1[i][o] = fmaxf(acc, 0.f);
    }
    __syncthreads();

    // ---- fc2: 120 -> 84, relu ----
    if (t < IPB*84) {
        int o = t % 84, i = t / 84;
        float acc = f2b[o];
        const float4* wr = (const float4*)(f2w + o*120);
        const float4* ar = (const float4*)&u.f.a1[i][0];
#pragma unroll
        for (int k = 0; k < 30; k++) {
            float4 w4 = wr[k], a4 = ar[k];
            acc += w4.x*a4.x + w4.y*a4.y + w4.z*a4.z + w4.w*a4.w;
        }
        u.f.a2[i][o] = fmaxf(acc, 0.f);
    }
    __syncthreads();

    // ---- fc3: 84 -> 64 (embeddings) ----
    if (t < IPB*64) {
        int o = t % 64, i = t / 64;
        float acc = f3b[o];
        const float4* wr = (const float4*)(f3w + o*84);
        const float4* ar = (const float4*)&u.f.a2[i][0];
#pragma unroll
        for (int k = 0; k < 21; k++) {
            float4 w4 = wr[k], a4 = ar[k];
            acc += w4.x*a4.x + w4.y*a4.y + w4.z*a4.z + w4.w*a4.w;
        }
        emb_out[((size_t)blockIdx.x*IPB + i)*64 + o] = acc;
    }
}

// Stage 1 of deterministic sum over all N*64 embeddings
__global__ __launch_bounds__(256) void reduce_emb(const float* __restrict__ emb,
                                                  float* __restrict__ part, int total) {
    __shared__ float s_[256];
    const int t = threadIdx.x;
    const int chunk = total / 256;
    const float* base = emb + (size_t)blockIdx.x * chunk;
    float s = 0.f;
    for (int j = t; j < chunk; j += 256) s += base[j];
    s_[t] = s; __syncthreads();
    for (int off = 128; off > 0; off >>= 1) {
        if (t < off) s_[t] += s_[t + off];
        __syncthreads();
    }
    if (t == 0) part[blockIdx.x] = s_[0];
}

// Stage 2: 256 partials -> proto = sum / NUM_CLASSES
__global__ __launch_bounds__(256) void reduce_part(const float* __restrict__ part,
                                                   float* __restrict__ proto) {
    __shared__ float s_[256];
    const int t = threadIdx.x;
    s_[t] = part[t]; __syncthreads();
    for (int off = 128; off > 0; off >>= 1) {
        if (t < off) s_[t] += s_[t + off];
        __syncthreads();
    }
    if (t == 0) proto[0] = s_[0] / 5.0f;
}

// Per-row softmax over 64, then |softmax - proto|, in place on d_out
__global__ __launch_bounds__(256) void softmax_abs(float* __restrict__ io,
                                                   const float* __restrict__ proto_p) {
    const int lane = threadIdx.x & 63;
    const int row = (blockIdx.x << 2) + (threadIdx.x >> 6);
    const float proto = proto_p[0];
    float e = io[(size_t)row*64 + lane];
    float m = e;
#pragma unroll
    for (int off = 32; off; off >>= 1) m = fmaxf(m, __shfl_xor(m, off));
    float p = expf(e - m);
    float s = p;
#pragma unroll
    for (int off = 32; off; off >>= 1) s += __shfl_xor(s, off);
    io[(size_t)row*64 + lane] = fabsf(p / s - proto);
}

extern "C" void kernel_launch(void* const* d_in, const int* in_sizes, int n_in,
                              void* d_out, int out_size, void* d_ws, size_t ws_size,
                              hipStream_t stream) {
    const float* x   = (const float*)d_in[0];
    const float* c1w = (const float*)d_in[1];
    const float* c1b = (const float*)d_in[2];
    const float* c2w = (const float*)d_in[3];
    const float* c2b = (const float*)d_in[4];
    const float* f1w = (const float*)d_in[5];
    const float* f1b = (const float*)d_in[6];
    const float* f2w = (const float*)d_in[7];
    const float* f2b = (const float*)d_in[8];
    const float* f3w = (const float*)d_in[9];
    const float* f3b = (const float*)d_in[10];
    float* out = (float*)d_out;

    float* part  = (float*)d_ws;   // 256 floats
    float* proto = part + 256;     // 1 float

    const int N = in_sizes[0] / 3072;   // 20480
    const int total = N * 64;

    lenet_fused<<<N/IPB, BLOCK, 0, stream>>>(x, c1w, c1b, c2w, c2b,
                                             f1w, f1b, f2w, f2b, f3w, f3b, out);
    reduce_emb<<<256, 256, 0, stream>>>(out, part, total);
    reduce_part<<<1, 256, 0, stream>>>(part, proto);
    softmax_abs<<<N/4, 256, 0, stream>>>(out, proto);
}

// Round 4
// 394.787 us; speedup vs baseline: 1.7410x; 1.7410x over previous
//
#include <hip/hip_runtime.h>
#include <math.h>

typedef __attribute__((ext_vector_type(8))) short short8;
typedef __attribute__((ext_vector_type(4))) float f32x4;
typedef __attribute__((ext_vector_type(4))) unsigned short us4v;

__device__ __forceinline__ unsigned short f2bf(float f) {
    unsigned u = __float_as_uint(f);
    return (unsigned short)((u + 0x7FFFu + ((u >> 16) & 1u)) >> 16);
}
__device__ __forceinline__ float bf2f(unsigned short h) {
    return __uint_as_float(((unsigned)h) << 16);
}

#define C1_SS 3464   // LDS elems per sample (3456 data + 8 pad)
#define C1_RS 36     // LDS row stride (32 data + 4 pad)

// conv1 + relu + pool2 via bf16 MFMA.
// M = 8 samples x 2 x-quads, N = co(y=2py) cols 0..5 | co(y=2py+1) cols 8..13,
// K = 20 blocks (ci,kappa) kx-padded to 8 -> 5 MFMA K-steps.
__global__ __launch_bounds__(256, 2) void conv1_mfma(
    const float* __restrict__ x, const float* __restrict__ c1w,
    const float* __restrict__ c1b, unsigned short* __restrict__ P1, int nblk)
{
    __shared__ __align__(16) unsigned short img[8 * C1_SS];  // 55424 B
    const int t = threadIdx.x;
    const int lane = t & 63, wave = t >> 6;
    const int grp = lane >> 4, c = lane & 15;
    const int s8 = c & 7, qh = c >> 3;

    // zero the pads (MFMA reads them; must be finite)
    for (int r = t; r < 768; r += 256)                 // 8*96 rows, elems 32..35
        *(uint2*)&img[r * C1_RS + 32] = make_uint2(0u, 0u);
    if (t < 8)                                          // sample tail elems 3456..3463
        *(uint4*)&img[t * C1_SS + 3456] = make_uint4(0u, 0u, 0u, 0u);

    // stage 8 images fp32 -> bf16 (coalesced float4 reads)
    const float4* xs = (const float4*)(x + (size_t)blockIdx.x * 24576);
    for (int f = t; f < 6144; f += 256) {
        float4 v = xs[f];
        int s = f / 768, w4 = f % 768;
        int ci = w4 >> 8, rem = w4 & 255, y = rem >> 3, xq = rem & 7;
        int de = s * C1_SS + (ci * 32 + y) * C1_RS + xq * 4;
        us4v pk = { f2bf(v.x), f2bf(v.y), f2bf(v.z), f2bf(v.w) };
        *(us4v*)&img[de] = pk;
    }

    // build weight fragments in registers: 5 steps x 4 x-offsets
    short8 wf[5][4];
#pragma unroll
    for (int s = 0; s < 5; s++) {
#pragma unroll
        for (int off = 0; off < 4; off++) {
            int b = s * 4 + grp;
            int ci = b / 6, kp = b % 6;
            short8 wv;
#pragma unroll
            for (int j = 0; j < 8; j++) {
                int kx = j - off;
                float v = 0.f;
                if (b < 18 && kx >= 0 && kx <= 4) {
                    if (c < 6 && kp <= 4)
                        v = c1w[c * 75 + ci * 25 + kp * 5 + kx];
                    else if (c >= 8 && c < 14 && kp >= 1)
                        v = c1w[(c - 8) * 75 + ci * 25 + (kp - 1) * 5 + kx];
                }
                wv[j] = (short)f2bf(v);
            }
            wf[s][off] = wv;
        }
    }
    const float bias = (c < 6) ? c1b[c] : 0.f;
    __syncthreads();

    // 56 items = 14 py x 4 quad-pairs over 4 waves
    for (int item = wave; item < 56; item += 4) {
        int py = item >> 2, qp = item & 3;
        int q = qp * 2 + qh;                       // this lane's A-side quad
        f32x4 ac0 = {0.f,0.f,0.f,0.f}, ac1 = ac0, ac2 = ac0, ac3 = ac0;
#pragma unroll
        for (int s = 0; s < 5; s++) {
            int b = s * 4 + grp; if (b > 17) b = 17;
            int ci = b / 6, kp = b % 6;
            int e = s8 * C1_SS + (ci * 32 + py * 2 + kp) * C1_RS + q * 4;
            union { us4v h[2]; short8 v; } af;
            af.h[0] = *(const us4v*)&img[e];
            af.h[1] = *(const us4v*)&img[e + 4];
            ac0 = __builtin_amdgcn_mfma_f32_16x16x32_bf16(af.v, wf[s][0], ac0, 0, 0, 0);
            ac1 = __builtin_amdgcn_mfma_f32_16x16x32_bf16(af.v, wf[s][1], ac1, 0, 0, 0);
            ac2 = __builtin_amdgcn_mfma_f32_16x16x32_bf16(af.v, wf[s][2], ac2, 0, 0, 0);
            ac3 = __builtin_amdgcn_mfma_f32_16x16x32_bf16(af.v, wf[s][3], ac3, 0, 0, 0);
        }
        // pool over x-pairs (in-lane) then y-pair (lane c <-> c+8)
        f32x4 pe, po;
#pragma unroll
        for (int i = 0; i < 4; i++) {
            pe[i] = fmaxf(ac0[i], ac1[i]);
            po[i] = fmaxf(ac2[i], ac3[i]);
        }
        f32x4 pe2, po2;
#pragma unroll
        for (int i = 0; i < 4; i++) {
            pe2[i] = fmaxf(pe[i], __shfl_xor(pe[i], 8));
            po2[i] = fmaxf(po[i], __shfl_xor(po[i], 8));
        }
        int qs = qp * 2 + (grp >> 1);              // this lane's D-side quad
        if (c < 6 && qs < 7) {
            int px0 = qs * 2;
#pragma unroll
            for (int i = 0; i < 4; i++) {
                int m = grp * 4 + i;
                int n = blockIdx.x * 8 + (m & 7);
                float v0 = fmaxf(pe2[i] + bias, 0.f);
                float v1 = fmaxf(po2[i] + bias, 0.f);
                unsigned pk = (unsigned)f2bf(v0) | ((unsigned)f2bf(v1) << 16);
                *(unsigned*)&P1[(size_t)n * 1176 + c * 196 + py * 14 + px0] = pk;
            }
        }
    }
}

#define C2_SS 1352   // LDS elems per sample (6*14 rows x 16 + 8 pad)

// conv2 + relu + pool2 via bf16 MFMA. M=16 samples, N=16 co,
// K = 30 blocks (ci,ky) kx-padded to 8 -> 8 MFMA K-steps; 2 x-parity W variants.
__global__ __launch_bounds__(256, 2) void conv2_mfma(
    const unsigned short* __restrict__ P1, const float* __restrict__ c2w,
    const float* __restrict__ c2b, unsigned short* __restrict__ P2)
{
    __shared__ __align__(16) unsigned short p1s[16 * C2_SS];  // 43264 B
    const int t = threadIdx.x;
    const int lane = t & 63, wave = t >> 6;
    const int grp = lane >> 4, c = lane & 15;

    // zero pads
    for (int r = t; r < 16 * 84; r += 256)
        *(unsigned*)&p1s[(r / 84) * C2_SS + (r % 84) * 16 + 14] = 0u;
    if (t < 16)
        *(uint4*)&p1s[t * C2_SS + 1344] = make_uint4(0u, 0u, 0u, 0u);

    // stage 16 samples of P1 (row stride 14 -> 16)
    const unsigned short* src = P1 + (size_t)blockIdx.x * 16 * 1176;
    for (int e = t; e < 16 * 1176; e += 256) {
        int s = e / 1176, r = e % 1176;
        int co = r / 196, rr = r % 196, y = rr / 14, xx = rr % 14;
        p1s[s * C2_SS + (co * 14 + y) * 16 + xx] = src[e];
    }

    // weight fragments: 8 steps x 2 parities
    short8 wf[8][2];
#pragma unroll
    for (int s = 0; s < 8; s++) {
#pragma unroll
        for (int off = 0; off < 2; off++) {
            int b = s * 4 + grp;
            short8 wv;
#pragma unroll
            for (int j = 0; j < 8; j++) {
                int kx = j - off;
                float v = 0.f;
                if (b < 30 && kx >= 0 && kx <= 4) {
                    int ci = b / 5, ky = b % 5;
                    v = c2w[c * 150 + ci * 25 + ky * 5 + kx];
                }
                wv[j] = (short)f2bf(v);
            }
            wf[s][off] = wv;
        }
    }
    const float bias = c2b[c];
    __syncthreads();

    for (int item = wave; item < 25; item += 4) {
        int py = item / 5, px = item % 5;
        f32x4 a00 = {0.f,0.f,0.f,0.f}, a01 = a00, a10 = a00, a11 = a00;
#pragma unroll
        for (int s = 0; s < 8; s++) {
            int b = s * 4 + grp; if (b > 29) b = 29;
            int ci = b / 5, ky = b % 5;
#pragma unroll
            for (int yo = 0; yo < 2; yo++) {
                int e = c * C2_SS + (ci * 14 + py * 2 + yo + ky) * 16 + px * 2;
                union { unsigned u[4]; short8 v; } af;
                af.u[0] = *(const unsigned*)&p1s[e];
                af.u[1] = *(const unsigned*)&p1s[e + 2];
                af.u[2] = *(const unsigned*)&p1s[e + 4];
                af.u[3] = *(const unsigned*)&p1s[e + 6];
                if (yo == 0) {
                    a00 = __builtin_amdgcn_mfma_f32_16x16x32_bf16(af.v, wf[s][0], a00, 0, 0, 0);
                    a01 = __builtin_amdgcn_mfma_f32_16x16x32_bf16(af.v, wf[s][1], a01, 0, 0, 0);
                } else {
                    a10 = __builtin_amdgcn_mfma_f32_16x16x32_bf16(af.v, wf[s][0], a10, 0, 0, 0);
                    a11 = __builtin_amdgcn_mfma_f32_16x16x32_bf16(af.v, wf[s][1], a11, 0, 0, 0);
                }
            }
        }
#pragma unroll
        for (int i = 0; i < 4; i++) {
            float mx = fmaxf(fmaxf(a00[i], a01[i]), fmaxf(a10[i], a11[i]));
            float v = fmaxf(mx + bias, 0.f);
            int n = blockIdx.x * 16 + grp * 4 + i;
            P2[(size_t)n * 400 + c * 25 + py * 5 + px] = f2bf(v);
        }
    }
}

// FC1->FC2->FC3 on VALU, 8 samples per block (weights L1/L2-amortized)
__global__ __launch_bounds__(256) void fc_fused(
    const unsigned short* __restrict__ P2,
    const float* __restrict__ f1w, const float* __restrict__ f1b,
    const float* __restrict__ f2w, const float* __restrict__ f2b,
    const float* __restrict__ f3w, const float* __restrict__ f3b,
    float* __restrict__ emb)
{
    __shared__ __align__(16) float p2s[8][404];
    __shared__ __align__(16) float a1s[8][124];
    __shared__ __align__(16) float a2s[8][88];
    const int t = threadIdx.x;
    const unsigned short* src = P2 + (size_t)blockIdx.x * 3200;
    for (int e = t; e < 3200; e += 256) p2s[e / 400][e % 400] = bf2f(src[e]);
    __syncthreads();
    for (int it = t; it < 960; it += 256) {
        int o = it >> 3, i = it & 7;
        float acc = f1b[o];
        const float4* wr = (const float4*)(f1w + o * 400);
        const float4* ar = (const float4*)&p2s[i][0];
#pragma unroll 4
        for (int k = 0; k < 100; k++) {
            float4 w4 = wr[k], a4 = ar[k];
            acc += w4.x * a4.x + w4.y * a4.y + w4.z * a4.z + w4.w * a4.w;
        }
        a1s[i][o] = fmaxf(acc, 0.f);
    }
    __syncthreads();
    for (int it = t; it < 672; it += 256) {
        int o = it >> 3, i = it & 7;
        float acc = f2b[o];
        const float4* wr = (const float4*)(f2w + o * 120);
        const float4* ar = (const float4*)&a1s[i][0];
#pragma unroll
        for (int k = 0; k < 30; k++) {
            float4 w4 = wr[k], a4 = ar[k];
            acc += w4.x * a4.x + w4.y * a4.y + w4.z * a4.z + w4.w * a4.w;
        }
        a2s[i][o] = fmaxf(acc, 0.f);
    }
    __syncthreads();
    for (int it = t; it < 512; it += 256) {
        int o = it >> 3, i = it & 7;
        float acc = f3b[o];
        const float4* wr = (const float4*)(f3w + o * 84);
        const float4* ar = (const float4*)&a2s[i][0];
#pragma unroll
        for (int k = 0; k < 21; k++) {
            float4 w4 = wr[k], a4 = ar[k];
            acc += w4.x * a4.x + w4.y * a4.y + w4.z * a4.z + w4.w * a4.w;
        }
        emb[((size_t)blockIdx.x * 8 + i) * 64 + o] = acc;
    }
}

// deterministic two-stage sum of all embeddings
__global__ __launch_bounds__(256) void reduce_emb(const float* __restrict__ emb,
                                                  float* __restrict__ part, int total) {
    __shared__ float s_[256];
    const int t = threadIdx.x;
    const int chunk = total / 256;
    const float* base = emb + (size_t)blockIdx.x * chunk;
    float s = 0.f;
    for (int j = t; j < chunk; j += 256) s += base[j];
    s_[t] = s; __syncthreads();
    for (int off = 128; off > 0; off >>= 1) {
        if (t < off) s_[t] += s_[t + off];
        __syncthreads();
    }
    if (t == 0) part[blockIdx.x] = s_[0];
}

__global__ __launch_bounds__(256) void reduce_part(const float* __restrict__ part,
                                                   float* __restrict__ proto) {
    __shared__ float s_[256];
    const int t = threadIdx.x;
    s_[t] = part[t]; __syncthreads();
    for (int off = 128; off > 0; off >>= 1) {
        if (t < off) s_[t] += s_[t + off];
        __syncthreads();
    }
    if (t == 0) proto[0] = s_[0] / 5.0f;
}

__global__ __launch_bounds__(256) void softmax_abs(float* __restrict__ io,
                                                   const float* __restrict__ proto_p) {
    const int lane = threadIdx.x & 63;
    const int row = (blockIdx.x << 2) + (threadIdx.x >> 6);
    const float proto = proto_p[0];
    float e = io[(size_t)row * 64 + lane];
    float m = e;
#pragma unroll
    for (int off = 32; off; off >>= 1) m = fmaxf(m, __shfl_xor(m, off));
    float p = expf(e - m);
    float s = p;
#pragma unroll
    for (int off = 32; off; off >>= 1) s += __shfl_xor(s, off);
    io[(size_t)row * 64 + lane] = fabsf(p / s - proto);
}

extern "C" void kernel_launch(void* const* d_in, const int* in_sizes, int n_in,
                              void* d_out, int out_size, void* d_ws, size_t ws_size,
                              hipStream_t stream) {
    const float* x   = (const float*)d_in[0];
    const float* c1w = (const float*)d_in[1];
    const float* c1b = (const float*)d_in[2];
    const float* c2w = (const float*)d_in[3];
    const float* c2b = (const float*)d_in[4];
    const float* f1w = (const float*)d_in[5];
    const float* f1b = (const float*)d_in[6];
    const float* f2w = (const float*)d_in[7];
    const float* f2b = (const float*)d_in[8];
    const float* f3w = (const float*)d_in[9];
    const float* f3b = (const float*)d_in[10];
    float* out = (float*)d_out;

    const int N = in_sizes[0] / 3072;            // 20480
    const size_t p1_bytes = (size_t)N * 1176 * 2;
    const size_t p2_bytes = (size_t)N * 400 * 2;
    unsigned short* P1 = (unsigned short*)d_ws;
    unsigned short* P2 = (unsigned short*)((char*)d_ws + p1_bytes);
    float* part  = (float*)((char*)d_ws + p1_bytes + p2_bytes);
    float* proto = part + 256;

    conv1_mfma<<<N / 8, 256, 0, stream>>>(x, c1w, c1b, P1, N / 8);
    conv2_mfma<<<N / 16, 256, 0, stream>>>(P1, c2w, c2b, P2);
    fc_fused<<<N / 8, 256, 0, stream>>>(P2, f1w, f1b, f2w, f2b, f3w, f3b, out);
    reduce_emb<<<256, 256, 0, stream>>>(out, part, N * 64);
    reduce_part<<<1, 256, 0, stream>>>(part, proto);
    softmax_abs<<<N / 4, 256, 0, stream>>>(out, proto);
}

// Round 5
// 243.649 us; speedup vs baseline: 2.8210x; 1.6203x over previous
//
#include <hip/hip_runtime.h>
#include <math.h>

typedef __attribute__((ext_vector_type(8))) short short8;
typedef __attribute__((ext_vector_type(4))) float f32x4;
typedef __attribute__((ext_vector_type(4))) unsigned short us4v;

__device__ __forceinline__ unsigned short f2bf(float f) {
    unsigned u = __float_as_uint(f);
    return (unsigned short)((u + 0x7FFFu + ((u >> 16) & 1u)) >> 16);
}
__device__ __forceinline__ float bf2f(unsigned short h) {
    return __uint_as_float(((unsigned)h) << 16);
}

#define C1_SS 3464   // LDS elems per sample (3456 data + 8 pad)
#define C1_RS 36     // LDS row stride (32 data + 4 pad)

// conv1 + relu + pool2 via bf16 MFMA.
__global__ __launch_bounds__(256, 2) void conv1_mfma(
    const float* __restrict__ x, const float* __restrict__ c1w,
    const float* __restrict__ c1b, unsigned short* __restrict__ P1, int nblk)
{
    __shared__ __align__(16) unsigned short img[8 * C1_SS];  // 55424 B
    const int t = threadIdx.x;
    const int lane = t & 63, wave = t >> 6;
    const int grp = lane >> 4, c = lane & 15;
    const int s8 = c & 7, qh = c >> 3;

    for (int r = t; r < 768; r += 256)
        *(uint2*)&img[r * C1_RS + 32] = make_uint2(0u, 0u);
    if (t < 8)
        *(uint4*)&img[t * C1_SS + 3456] = make_uint4(0u, 0u, 0u, 0u);

    const float4* xs = (const float4*)(x + (size_t)blockIdx.x * 24576);
    for (int f = t; f < 6144; f += 256) {
        float4 v = xs[f];
        int s = f / 768, w4 = f % 768;
        int ci = w4 >> 8, rem = w4 & 255, y = rem >> 3, xq = rem & 7;
        int de = s * C1_SS + (ci * 32 + y) * C1_RS + xq * 4;
        us4v pk = { f2bf(v.x), f2bf(v.y), f2bf(v.z), f2bf(v.w) };
        *(us4v*)&img[de] = pk;
    }

    short8 wf[5][4];
#pragma unroll
    for (int s = 0; s < 5; s++) {
#pragma unroll
        for (int off = 0; off < 4; off++) {
            int b = s * 4 + grp;
            int ci = b / 6, kp = b % 6;
            short8 wv;
#pragma unroll
            for (int j = 0; j < 8; j++) {
                int kx = j - off;
                float v = 0.f;
                if (b < 18 && kx >= 0 && kx <= 4) {
                    if (c < 6 && kp <= 4)
                        v = c1w[c * 75 + ci * 25 + kp * 5 + kx];
                    else if (c >= 8 && c < 14 && kp >= 1)
                        v = c1w[(c - 8) * 75 + ci * 25 + (kp - 1) * 5 + kx];
                }
                wv[j] = (short)f2bf(v);
            }
            wf[s][off] = wv;
        }
    }
    const float bias = (c < 6) ? c1b[c] : 0.f;
    __syncthreads();

    for (int item = wave; item < 56; item += 4) {
        int py = item >> 2, qp = item & 3;
        int q = qp * 2 + qh;
        f32x4 ac0 = {0.f,0.f,0.f,0.f}, ac1 = ac0, ac2 = ac0, ac3 = ac0;
#pragma unroll
        for (int s = 0; s < 5; s++) {
            int b = s * 4 + grp; if (b > 17) b = 17;
            int ci = b / 6, kp = b % 6;
            int e = s8 * C1_SS + (ci * 32 + py * 2 + kp) * C1_RS + q * 4;
            union { us4v h[2]; short8 v; } af;
            af.h[0] = *(const us4v*)&img[e];
            af.h[1] = *(const us4v*)&img[e + 4];
            ac0 = __builtin_amdgcn_mfma_f32_16x16x32_bf16(af.v, wf[s][0], ac0, 0, 0, 0);
            ac1 = __builtin_amdgcn_mfma_f32_16x16x32_bf16(af.v, wf[s][1], ac1, 0, 0, 0);
            ac2 = __builtin_amdgcn_mfma_f32_16x16x32_bf16(af.v, wf[s][2], ac2, 0, 0, 0);
            ac3 = __builtin_amdgcn_mfma_f32_16x16x32_bf16(af.v, wf[s][3], ac3, 0, 0, 0);
        }
        f32x4 pe, po;
#pragma unroll
        for (int i = 0; i < 4; i++) {
            pe[i] = fmaxf(ac0[i], ac1[i]);
            po[i] = fmaxf(ac2[i], ac3[i]);
        }
        f32x4 pe2, po2;
#pragma unroll
        for (int i = 0; i < 4; i++) {
            pe2[i] = fmaxf(pe[i], __shfl_xor(pe[i], 8));
            po2[i] = fmaxf(po[i], __shfl_xor(po[i], 8));
        }
        int qs = qp * 2 + (grp >> 1);
        if (c < 6 && qs < 7) {
            int px0 = qs * 2;
#pragma unroll
            for (int i = 0; i < 4; i++) {
                int m = grp * 4 + i;
                int n = blockIdx.x * 8 + (m & 7);
                float v0 = fmaxf(pe2[i] + bias, 0.f);
                float v1 = fmaxf(po2[i] + bias, 0.f);
                unsigned pk = (unsigned)f2bf(v0) | ((unsigned)f2bf(v1) << 16);
                *(unsigned*)&P1[(size_t)n * 1176 + c * 196 + py * 14 + px0] = pk;
            }
        }
    }
}

#define C2_SS 1352

// conv2 + relu + pool2 via bf16 MFMA.
__global__ __launch_bounds__(256, 2) void conv2_mfma(
    const unsigned short* __restrict__ P1, const float* __restrict__ c2w,
    const float* __restrict__ c2b, unsigned short* __restrict__ P2)
{
    __shared__ __align__(16) unsigned short p1s[16 * C2_SS];  // 43264 B
    const int t = threadIdx.x;
    const int lane = t & 63, wave = t >> 6;
    const int grp = lane >> 4, c = lane & 15;

    for (int r = t; r < 16 * 84; r += 256)
        *(unsigned*)&p1s[(r / 84) * C2_SS + (r % 84) * 16 + 14] = 0u;
    if (t < 16)
        *(uint4*)&p1s[t * C2_SS + 1344] = make_uint4(0u, 0u, 0u, 0u);

    const unsigned short* src = P1 + (size_t)blockIdx.x * 16 * 1176;
    for (int e = t; e < 16 * 1176; e += 256) {
        int s = e / 1176, r = e % 1176;
        int co = r / 196, rr = r % 196, y = rr / 14, xx = rr % 14;
        p1s[s * C2_SS + (co * 14 + y) * 16 + xx] = src[e];
    }

    short8 wf[8][2];
#pragma unroll
    for (int s = 0; s < 8; s++) {
#pragma unroll
        for (int off = 0; off < 2; off++) {
            int b = s * 4 + grp;
            short8 wv;
#pragma unroll
            for (int j = 0; j < 8; j++) {
                int kx = j - off;
                float v = 0.f;
                if (b < 30 && kx >= 0 && kx <= 4) {
                    int ci = b / 5, ky = b % 5;
                    v = c2w[c * 150 + ci * 25 + ky * 5 + kx];
                }
                wv[j] = (short)f2bf(v);
            }
            wf[s][off] = wv;
        }
    }
    const float bias = c2b[c];
    __syncthreads();

    for (int item = wave; item < 25; item += 4) {
        int py = item / 5, px = item % 5;
        f32x4 a00 = {0.f,0.f,0.f,0.f}, a01 = a00, a10 = a00, a11 = a00;
#pragma unroll
        for (int s = 0; s < 8; s++) {
            int b = s * 4 + grp; if (b > 29) b = 29;
            int ci = b / 5, ky = b % 5;
#pragma unroll
            for (int yo = 0; yo < 2; yo++) {
                int e = c * C2_SS + (ci * 14 + py * 2 + yo + ky) * 16 + px * 2;
                union { unsigned u[4]; short8 v; } af;
                af.u[0] = *(const unsigned*)&p1s[e];
                af.u[1] = *(const unsigned*)&p1s[e + 2];
                af.u[2] = *(const unsigned*)&p1s[e + 4];
                af.u[3] = *(const unsigned*)&p1s[e + 6];
                if (yo == 0) {
                    a00 = __builtin_amdgcn_mfma_f32_16x16x32_bf16(af.v, wf[s][0], a00, 0, 0, 0);
                    a01 = __builtin_amdgcn_mfma_f32_16x16x32_bf16(af.v, wf[s][1], a01, 0, 0, 0);
                } else {
                    a10 = __builtin_amdgcn_mfma_f32_16x16x32_bf16(af.v, wf[s][0], a10, 0, 0, 0);
                    a11 = __builtin_amdgcn_mfma_f32_16x16x32_bf16(af.v, wf[s][1], a11, 0, 0, 0);
                }
            }
        }
#pragma unroll
        for (int i = 0; i < 4; i++) {
            float mx = fmaxf(fmaxf(a00[i], a01[i]), fmaxf(a10[i], a11[i]));
            float v = fmaxf(mx + bias, 0.f);
            int n = blockIdx.x * 16 + grp * 4 + i;
            P2[(size_t)n * 400 + c * 25 + py * 5 + px] = f2bf(v);
        }
    }
}

// one-shot conversion of FC weights to zero-padded bf16 tiles
__global__ __launch_bounds__(256) void prep_weights(
    const float* __restrict__ f1w, const float* __restrict__ f2w,
    const float* __restrict__ f3w,
    unsigned short* __restrict__ wb1, unsigned short* __restrict__ wb2,
    unsigned short* __restrict__ wb3)
{
    const int t0 = blockIdx.x * 256 + threadIdx.x;
    const int stride = gridDim.x * 256;
    for (int i = t0; i < 128 * 416; i += stride) {
        int o = i / 416, k = i % 416;
        wb1[i] = f2bf((o < 120 && k < 400) ? f1w[o * 400 + k] : 0.f);
    }
    for (int i = t0; i < 96 * 128; i += stride) {
        int o = i / 128, k = i % 128;
        wb2[i] = f2bf((o < 84 && k < 120) ? f2w[o * 120 + k] : 0.f);
    }
    for (int i = t0; i < 64 * 96; i += stride) {
        int o = i / 96, k = i % 96;
        wb3[i] = f2bf((k < 84) ? f3w[o * 84 + k] : 0.f);
    }
}

#define FCS 32    // samples per block
#define P2S 424   // LDS row strides (mod-32-word = 20/4/20 -> free 2-way only)
#define A1S 136
#define A2S 104

// FC1->FC2->FC3 via bf16 MFMA. M=32 samples (2 tiles), waves split N-tiles.
__global__ __launch_bounds__(256, 3) void fc_mfma(
    const unsigned short* __restrict__ P2,
    const unsigned short* __restrict__ wb1, const float* __restrict__ f1b,
    const unsigned short* __restrict__ wb2, const float* __restrict__ f2b,
    const unsigned short* __restrict__ wb3, const float* __restrict__ f3b,
    float* __restrict__ emb)
{
    __shared__ __align__(16) unsigned short p2s[FCS * P2S];  // 27136 B
    __shared__ __align__(16) unsigned short a1s[FCS * A1S];  //  8704 B
    __shared__ __align__(16) unsigned short a2s[FCS * A2S];  //  6656 B
    const int t = threadIdx.x, lane = t & 63, w = t >> 6;
    const int grp = lane >> 4, c = lane & 15;

    // zero p2s K-pad (k = 400..415)
    if (t < 64) {
        int s = t >> 1, h = t & 1;
        *(uint4*)&p2s[s * P2S + 400 + h * 8] = make_uint4(0u, 0u, 0u, 0u);
    }
    // stage P2 (bf16, 8 elems per uint4)
    const uint4* src = (const uint4*)(P2 + (size_t)blockIdx.x * FCS * 400);
    for (int i = t; i < FCS * 50; i += 256) {
        int s = i / 50, k8 = i % 50;
        *(uint4*)&p2s[s * P2S + k8 * 8] = src[i];
    }
    __syncthreads();

    const int m = w & 1;          // sample tile: rows m*16..m*16+15
    const int arow = m * 16 + c;  // A-operand row (sample)

    // ---- FC1: K=416 (13 steps), N-tiles 0..7 (o 0..127) ----
    {
        const int n0 = (w >> 1) * 4;
        f32x4 acc[4] = {{0.f,0.f,0.f,0.f},{0.f,0.f,0.f,0.f},{0.f,0.f,0.f,0.f},{0.f,0.f,0.f,0.f}};
        const int sb = arow * P2S;
#pragma unroll
        for (int ks = 0; ks < 13; ks++) {
            short8 a = *(const short8*)&p2s[sb + ks * 32 + grp * 8];
#pragma unroll
            for (int j = 0; j < 4; j++) {
                int o = (n0 + j) * 16 + c;
                short8 b = *(const short8*)&wb1[o * 416 + ks * 32 + grp * 8];
                acc[j] = __builtin_amdgcn_mfma_f32_16x16x32_bf16(a, b, acc[j], 0, 0, 0);
            }
        }
#pragma unroll
        for (int j = 0; j < 4; j++) {
            int o = (n0 + j) * 16 + c;
            float bias = (o < 120) ? f1b[o] : 0.f;
#pragma unroll
            for (int i = 0; i < 4; i++) {
                int s = m * 16 + grp * 4 + i;
                a1s[s * A1S + o] = f2bf(fmaxf(acc[j][i] + bias, 0.f));
            }
        }
    }
    __syncthreads();

    // ---- FC2: K=128 (4 steps), N-tiles 0..5 (o 0..95) ----
    {
        const int n0 = (w >> 1) * 3;
        f32x4 acc[3] = {{0.f,0.f,0.f,0.f},{0.f,0.f,0.f,0.f},{0.f,0.f,0.f,0.f}};
        const int sb = arow * A1S;
#pragma unroll
        for (int ks = 0; ks < 4; ks++) {
            short8 a = *(const short8*)&a1s[sb + ks * 32 + grp * 8];
#pragma unroll
            for (int j = 0; j < 3; j++) {
                int o = (n0 + j) * 16 + c;
                short8 b = *(const short8*)&wb2[o * 128 + ks * 32 + grp * 8];
                acc[j] = __builtin_amdgcn_mfma_f32_16x16x32_bf16(a, b, acc[j], 0, 0, 0);
            }
        }
#pragma unroll
        for (int j = 0; j < 3; j++) {
            int o = (n0 + j) * 16 + c;
            float bias = (o < 84) ? f2b[o] : 0.f;
#pragma unroll
            for (int i = 0; i < 4; i++) {
                int s = m * 16 + grp * 4 + i;
                a2s[s * A2S + o] = f2bf(fmaxf(acc[j][i] + bias, 0.f));
            }
        }
    }
    __syncthreads();

    // ---- FC3: K=96 (3 steps), N-tiles 0..3 (o 0..63), no relu ----
    {
        const int n0 = (w >> 1) * 2;
        f32x4 acc[2] = {{0.f,0.f,0.f,0.f},{0.f,0.f,0.f,0.f}};
        const int sb = arow * A2S;
#pragma unroll
        for (int ks = 0; ks < 3; ks++) {
            short8 a = *(const short8*)&a2s[sb + ks * 32 + grp * 8];
#pragma unroll
            for (int j = 0; j < 2; j++) {
                int o = (n0 + j) * 16 + c;
                short8 b = *(const short8*)&wb3[o * 96 + ks * 32 + grp * 8];
                acc[j] = __builtin_amdgcn_mfma_f32_16x16x32_bf16(a, b, acc[j], 0, 0, 0);
            }
        }
#pragma unroll
        for (int j = 0; j < 2; j++) {
            int o = (n0 + j) * 16 + c;
            float bias = f3b[o];
#pragma unroll
            for (int i = 0; i < 4; i++) {
                int s = m * 16 + grp * 4 + i;
                emb[((size_t)blockIdx.x * FCS + s) * 64 + o] = acc[j][i] + bias;
            }
        }
    }
}

// deterministic two-stage sum of all embeddings
__global__ __launch_bounds__(256) void reduce_emb(const float* __restrict__ emb,
                                                  float* __restrict__ part, int total) {
    __shared__ float s_[256];
    const int t = threadIdx.x;
    const int chunk = total / 256;
    const float* base = emb + (size_t)blockIdx.x * chunk;
    float s = 0.f;
    for (int j = t; j < chunk; j += 256) s += base[j];
    s_[t] = s; __syncthreads();
    for (int off = 128; off > 0; off >>= 1) {
        if (t < off) s_[t] += s_[t + off];
        __syncthreads();
    }
    if (t == 0) part[blockIdx.x] = s_[0];
}

__global__ __launch_bounds__(256) void reduce_part(const float* __restrict__ part,
                                                   float* __restrict__ proto) {
    __shared__ float s_[256];
    const int t = threadIdx.x;
    s_[t] = part[t]; __syncthreads();
    for (int off = 128; off > 0; off >>= 1) {
        if (t < off) s_[t] += s_[t + off];
        __syncthreads();
    }
    if (t == 0) proto[0] = s_[0] / 5.0f;
}

__global__ __launch_bounds__(256) void softmax_abs(float* __restrict__ io,
                                                   const float* __restrict__ proto_p) {
    const int lane = threadIdx.x & 63;
    const int row = (blockIdx.x << 2) + (threadIdx.x >> 6);
    const float proto = proto_p[0];
    float e = io[(size_t)row * 64 + lane];
    float m = e;
#pragma unroll
    for (int off = 32; off; off >>= 1) m = fmaxf(m, __shfl_xor(m, off));
    float p = expf(e - m);
    float s = p;
#pragma unroll
    for (int off = 32; off; off >>= 1) s += __shfl_xor(s, off);
    io[(size_t)row * 64 + lane] = fabsf(p / s - proto);
}

extern "C" void kernel_launch(void* const* d_in, const int* in_sizes, int n_in,
                              void* d_out, int out_size, void* d_ws, size_t ws_size,
                              hipStream_t stream) {
    const float* x   = (const float*)d_in[0];
    const float* c1w = (const float*)d_in[1];
    const float* c1b = (const float*)d_in[2];
    const float* c2w = (const float*)d_in[3];
    const float* c2b = (const float*)d_in[4];
    const float* f1w = (const float*)d_in[5];
    const float* f1b = (const float*)d_in[6];
    const float* f2w = (const float*)d_in[7];
    const float* f2b = (const float*)d_in[8];
    const float* f3w = (const float*)d_in[9];
    const float* f3b = (const float*)d_in[10];
    float* out = (float*)d_out;

    const int N = in_sizes[0] / 3072;            // 20480
    const size_t p1_bytes = (size_t)N * 1176 * 2;
    const size_t p2_bytes = (size_t)N * 400 * 2;
    unsigned short* P1 = (unsigned short*)d_ws;
    unsigned short* P2 = (unsigned short*)((char*)d_ws + p1_bytes);
    char* tail = (char*)d_ws + p1_bytes + p2_bytes;
    float* part  = (float*)tail;                  // 256 floats
    float* proto = part + 256;                    // 1 float
    unsigned short* wb1 = (unsigned short*)(tail + 2048);          // 128x416
    unsigned short* wb2 = wb1 + 128 * 416;                          // 96x128
    unsigned short* wb3 = wb2 + 96 * 128;                           // 64x96

    prep_weights<<<64, 256, 0, stream>>>(f1w, f2w, f3w, wb1, wb2, wb3);
    conv1_mfma<<<N / 8, 256, 0, stream>>>(x, c1w, c1b, P1, N / 8);
    conv2_mfma<<<N / 16, 256, 0, stream>>>(P1, c2w, c2b, P2);
    fc_mfma<<<N / 32, 256, 0, stream>>>(P2, wb1, f1b, wb2, f2b, wb3, f3b, out);
    reduce_emb<<<256, 256, 0, stream>>>(out, part, N * 64);
    reduce_part<<<1, 256, 0, stream>>>(part, proto);
    softmax_abs<<<N / 4, 256, 0, stream>>>(out, proto);
}

// Round 6
// 152.532 us; speedup vs baseline: 4.5061x; 1.5974x over previous
//
#include <hip/hip_runtime.h>
#include <math.h>

typedef __attribute__((ext_vector_type(8))) short short8;
typedef __attribute__((ext_vector_type(4))) float f32x4;
typedef __attribute__((ext_vector_type(4))) unsigned short us4v;

__device__ __forceinline__ unsigned short f2bf(float f) {
    unsigned u = __float_as_uint(f);
    return (unsigned short)((u + 0x7FFFu + ((u >> 16) & 1u)) >> 16);
}
__device__ __forceinline__ float bf2f(unsigned short h) {
    return __uint_as_float(((unsigned)h) << 16);
}

#define C1_SS 3464   // LDS elems per sample (3456 data + 8 pad)
#define C1_RS 36     // LDS row stride (32 data + 4 pad)
#define P1_SS 1352   // P1 record per sample: [6*14 rows][16] + 8 tail pad

// conv1 + relu + pool2 via bf16 MFMA. 4 samples/block, LDS-staged output.
// A: row = sample(2b)|quad(2b), K = (ci,kp) blocks kx-padded to 8.
// B (from c1wf): col c -> co 0..5 @ y-even (cols 0-5) / y-odd (cols 8-13).
__global__ __launch_bounds__(256, 4) void conv1_mfma(
    const float* __restrict__ x, const unsigned short* __restrict__ c1wf,
    const float* __restrict__ c1b, unsigned short* __restrict__ P1)
{
    __shared__ __align__(16) unsigned short img[4 * C1_SS];   // 27712 B
    __shared__ __align__(16) unsigned short outs[4 * P1_SS];  // 10816 B
    const int t = threadIdx.x;
    const int lane = t & 63, w = t >> 6;
    const int grp = lane >> 4, c = lane & 15;
    const int s4 = c & 3, qd = c >> 2;

    // zero output staging (data + pads)
    for (int e = t; e < 676; e += 256)
        ((uint4*)outs)[e] = make_uint4(0u, 0u, 0u, 0u);
    // zero img row pads (elems 32..35 of 4*96 rows) + sample tails
    for (int r = t; r < 384; r += 256)
        *(uint2*)&img[r * C1_RS + 32] = make_uint2(0u, 0u);
    if (t < 4)
        *(uint4*)&img[t * C1_SS + 3456] = make_uint4(0u, 0u, 0u, 0u);

    // stage 4 images fp32 -> bf16 (pow2 index math only)
    const float4* xs = (const float4*)(x + (size_t)blockIdx.x * 12288);
#pragma unroll
    for (int s = 0; s < 4; s++) {
#pragma unroll
        for (int j = 0; j < 3; j++) {
            int w4 = j * 256 + t;                 // 0..767
            float4 v = xs[s * 768 + w4];
            int ci = w4 >> 8, rem = w4 & 255, y = rem >> 3, xq = rem & 7;
            int de = s * C1_SS + (ci * 32 + y) * C1_RS + xq * 4;
            us4v pk = { f2bf(v.x), f2bf(v.y), f2bf(v.z), f2bf(v.w) };
            *(us4v*)&img[de] = pk;
        }
    }

    // weight fragments (precomputed order): c1wf[s][off][grp][c][8]
    short8 wf[5][4];
#pragma unroll
    for (int s = 0; s < 5; s++)
#pragma unroll
        for (int off = 0; off < 4; off++)
            wf[s][off] = *(const short8*)&c1wf[(((s * 4 + off) * 4 + grp) * 16 + c) * 8];
    int ciA[5], kpA[5];
#pragma unroll
    for (int s = 0; s < 5; s++) {
        int b = s * 4 + grp; if (b > 17) b = 17;   // clamped dup has zero weights
        ciA[s] = b / 6; kpA[s] = b % 6;
    }
    const float bias = (c < 6) ? c1b[c] : 0.f;
    __syncthreads();

    // 28 items = 14 py x 2 quad-groups over 4 waves
    for (int item = w; item < 28; item += 4) {
        int py = item >> 1, g = item & 1;
        int q = g * 4 + qd;                        // A-side quad (x = q*4..q*4+7)
        f32x4 ac0 = {0.f,0.f,0.f,0.f}, ac1 = ac0, ac2 = ac0, ac3 = ac0;
#pragma unroll
        for (int s = 0; s < 5; s++) {
            int e = s4 * C1_SS + (ciA[s] * 32 + py * 2 + kpA[s]) * C1_RS + q * 4;
            union { us4v h[2]; short8 v; } af;
            af.h[0] = *(const us4v*)&img[e];
            af.h[1] = *(const us4v*)&img[e + 4];
            ac0 = __builtin_amdgcn_mfma_f32_16x16x32_bf16(af.v, wf[s][0], ac0, 0, 0, 0);
            ac1 = __builtin_amdgcn_mfma_f32_16x16x32_bf16(af.v, wf[s][1], ac1, 0, 0, 0);
            ac2 = __builtin_amdgcn_mfma_f32_16x16x32_bf16(af.v, wf[s][2], ac2, 0, 0, 0);
            ac3 = __builtin_amdgcn_mfma_f32_16x16x32_bf16(af.v, wf[s][3], ac3, 0, 0, 0);
        }
        // pool x-pairs in-lane, y-pair across lane c <-> c+8
        f32x4 pe, po, pe2, po2;
#pragma unroll
        for (int i = 0; i < 4; i++) {
            pe[i] = fmaxf(ac0[i], ac1[i]);
            po[i] = fmaxf(ac2[i], ac3[i]);
        }
#pragma unroll
        for (int i = 0; i < 4; i++) {
            pe2[i] = fmaxf(pe[i], __shfl_xor(pe[i], 8));
            po2[i] = fmaxf(po[i], __shfl_xor(po[i], 8));
        }
        if (c < 6) {
#pragma unroll
            for (int i = 0; i < 4; i++) {
                int m = grp * 4 + i;               // D row: sample = m&3, quad = m>>2
                int qo = g * 4 + (m >> 2);
                if (qo < 7) {
                    int smp = m & 3;
                    float v0 = fmaxf(pe2[i] + bias, 0.f);
                    float v1 = fmaxf(po2[i] + bias, 0.f);
                    unsigned pk = (unsigned)f2bf(v0) | ((unsigned)f2bf(v1) << 16);
                    *(unsigned*)&outs[smp * P1_SS + (c * 14 + py) * 16 + qo * 2] = pk;
                }
            }
        }
    }
    __syncthreads();

    // coalesced dump: P1 record layout == conv2 LDS layout
    uint4* dst = (uint4*)(P1 + (size_t)blockIdx.x * 4 * P1_SS);
    for (int e = t; e < 676; e += 256)
        dst[e] = ((const uint4*)outs)[e];
}

// conv2 + relu + pool2 via bf16 MFMA. 16 samples/block; staging = pure copy.
__global__ __launch_bounds__(256, 3) void conv2_mfma(
    const unsigned short* __restrict__ P1, const unsigned short* __restrict__ c2wf,
    const float* __restrict__ c2b, unsigned short* __restrict__ P2)
{
    __shared__ __align__(16) unsigned short p1s[16 * P1_SS];  // 43264 B
    const int t = threadIdx.x;
    const int lane = t & 63;
    const int wave = t >> 6;
    const int grp = lane >> 4, c = lane & 15;

    // stage: contiguous vector copy (P1 already in native layout, pads zeroed)
    {
        const uint4* src = (const uint4*)(P1 + (size_t)blockIdx.x * 16 * P1_SS);
        uint4* dst = (uint4*)p1s;
        for (int e = t; e < 2704; e += 256) dst[e] = src[e];
    }

    // weight fragments: c2wf[s][off][grp][c][8]
    short8 wf[8][2];
#pragma unroll
    for (int s = 0; s < 8; s++)
#pragma unroll
        for (int off = 0; off < 2; off++)
            wf[s][off] = *(const short8*)&c2wf[(((s * 2 + off) * 4 + grp) * 16 + c) * 8];
    int ciA[8], kyA[8];
#pragma unroll
    for (int s = 0; s < 8; s++) {
        int b = s * 4 + grp; if (b > 29) b = 29;   // clamped dup has zero weights
        ciA[s] = b / 5; kyA[s] = b % 5;
    }
    const float bias = c2b[c];
    __syncthreads();

    for (int item = wave; item < 25; item += 4) {
        int py = item / 5, px = item % 5;
        f32x4 a00 = {0.f,0.f,0.f,0.f}, a01 = a00, a10 = a00, a11 = a00;
#pragma unroll
        for (int s = 0; s < 8; s++) {
            int rbase = ciA[s] * 14 + kyA[s] + py * 2;
#pragma unroll
            for (int yo = 0; yo < 2; yo++) {
                int e = c * P1_SS + (rbase + yo) * 16 + px * 2;
                union { unsigned u[4]; short8 v; } af;
                af.u[0] = *(const unsigned*)&p1s[e];
                af.u[1] = *(const unsigned*)&p1s[e + 2];
                af.u[2] = *(const unsigned*)&p1s[e + 4];
                af.u[3] = *(const unsigned*)&p1s[e + 6];
                if (yo == 0) {
                    a00 = __builtin_amdgcn_mfma_f32_16x16x32_bf16(af.v, wf[s][0], a00, 0, 0, 0);
                    a01 = __builtin_amdgcn_mfma_f32_16x16x32_bf16(af.v, wf[s][1], a01, 0, 0, 0);
                } else {
                    a10 = __builtin_amdgcn_mfma_f32_16x16x32_bf16(af.v, wf[s][0], a10, 0, 0, 0);
                    a11 = __builtin_amdgcn_mfma_f32_16x16x32_bf16(af.v, wf[s][1], a11, 0, 0, 0);
                }
            }
        }
#pragma unroll
        for (int i = 0; i < 4; i++) {
            float mx = fmaxf(fmaxf(a00[i], a01[i]), fmaxf(a10[i], a11[i]));
            float v = fmaxf(mx + bias, 0.f);
            int n = blockIdx.x * 16 + grp * 4 + i;
            P2[(size_t)n * 400 + c * 25 + py * 5 + px] = f2bf(v);
        }
    }
}

// one-shot conversion: FC weights to padded bf16 tiles + conv weight fragments
__global__ __launch_bounds__(256) void prep_weights(
    const float* __restrict__ c1w, const float* __restrict__ c2w,
    const float* __restrict__ f1w, const float* __restrict__ f2w,
    const float* __restrict__ f3w,
    unsigned short* __restrict__ wb1, unsigned short* __restrict__ wb2,
    unsigned short* __restrict__ wb3,
    unsigned short* __restrict__ c1wf, unsigned short* __restrict__ c2wf)
{
    const int t0 = blockIdx.x * 256 + threadIdx.x;
    const int stride = gridDim.x * 256;
    for (int i = t0; i < 128 * 416; i += stride) {
        int o = i / 416, k = i % 416;
        wb1[i] = f2bf((o < 120 && k < 400) ? f1w[o * 400 + k] : 0.f);
    }
    for (int i = t0; i < 96 * 128; i += stride) {
        int o = i / 128, k = i % 128;
        wb2[i] = f2bf((o < 84 && k < 120) ? f2w[o * 120 + k] : 0.f);
    }
    for (int i = t0; i < 64 * 96; i += stride) {
        int o = i / 96, k = i % 96;
        wb3[i] = f2bf((k < 84) ? f3w[o * 84 + k] : 0.f);
    }
    // c1wf[s(5)][off(4)][grp(4)][c(16)][j(8)]
    for (int i = t0; i < 10240; i += stride) {
        int j = i & 7, c = (i >> 3) & 15, grp = (i >> 7) & 3;
        int off = (i >> 9) & 3, s = i >> 11;
        int b = s * 4 + grp;
        int ci = b / 6, kp = b % 6;
        int kx = j - off;
        float v = 0.f;
        if (b < 18 && kx >= 0 && kx <= 4) {
            if (c < 6 && kp <= 4)
                v = c1w[c * 75 + ci * 25 + kp * 5 + kx];
            else if (c >= 8 && c < 14 && kp >= 1)
                v = c1w[(c - 8) * 75 + ci * 25 + (kp - 1) * 5 + kx];
        }
        c1wf[i] = f2bf(v);
    }
    // c2wf[s(8)][off(2)][grp(4)][c(16)][j(8)]
    for (int i = t0; i < 8192; i += stride) {
        int j = i & 7, c = (i >> 3) & 15, grp = (i >> 7) & 3;
        int off = (i >> 9) & 1, s = i >> 10;
        int b = s * 4 + grp;
        int kx = j - off;
        float v = 0.f;
        if (b < 30 && kx >= 0 && kx <= 4) {
            int ci = b / 5, ky = b % 5;
            v = c2w[c * 150 + ci * 25 + ky * 5 + kx];
        }
        c2wf[i] = f2bf(v);
    }
}

#define FCS 32
#define P2S 424
#define A1S 136
#define A2S 104

// FC1->FC2->FC3 via bf16 MFMA (unchanged from round 4)
__global__ __launch_bounds__(256, 3) void fc_mfma(
    const unsigned short* __restrict__ P2,
    const unsigned short* __restrict__ wb1, const float* __restrict__ f1b,
    const unsigned short* __restrict__ wb2, const float* __restrict__ f2b,
    const unsigned short* __restrict__ wb3, const float* __restrict__ f3b,
    float* __restrict__ emb)
{
    __shared__ __align__(16) unsigned short p2s[FCS * P2S];
    __shared__ __align__(16) unsigned short a1s[FCS * A1S];
    __shared__ __align__(16) unsigned short a2s[FCS * A2S];
    const int t = threadIdx.x, lane = t & 63, w = t >> 6;
    const int grp = lane >> 4, c = lane & 15;

    if (t < 64) {
        int s = t >> 1, h = t & 1;
        *(uint4*)&p2s[s * P2S + 400 + h * 8] = make_uint4(0u, 0u, 0u, 0u);
    }
    const uint4* src = (const uint4*)(P2 + (size_t)blockIdx.x * FCS * 400);
    for (int i = t; i < FCS * 50; i += 256) {
        int s = i / 50, k8 = i % 50;
        *(uint4*)&p2s[s * P2S + k8 * 8] = src[i];
    }
    __syncthreads();

    const int m = w & 1;
    const int arow = m * 16 + c;

    {
        const int n0 = (w >> 1) * 4;
        f32x4 acc[4] = {{0.f,0.f,0.f,0.f},{0.f,0.f,0.f,0.f},{0.f,0.f,0.f,0.f},{0.f,0.f,0.f,0.f}};
        const int sb = arow * P2S;
#pragma unroll
        for (int ks = 0; ks < 13; ks++) {
            short8 a = *(const short8*)&p2s[sb + ks * 32 + grp * 8];
#pragma unroll
            for (int j = 0; j < 4; j++) {
                int o = (n0 + j) * 16 + c;
                short8 b = *(const short8*)&wb1[o * 416 + ks * 32 + grp * 8];
                acc[j] = __builtin_amdgcn_mfma_f32_16x16x32_bf16(a, b, acc[j], 0, 0, 0);
            }
        }
#pragma unroll
        for (int j = 0; j < 4; j++) {
            int o = (n0 + j) * 16 + c;
            float bias = (o < 120) ? f1b[o] : 0.f;
#pragma unroll
            for (int i = 0; i < 4; i++) {
                int s = m * 16 + grp * 4 + i;
                a1s[s * A1S + o] = f2bf(fmaxf(acc[j][i] + bias, 0.f));
            }
        }
    }
    __syncthreads();

    {
        const int n0 = (w >> 1) * 3;
        f32x4 acc[3] = {{0.f,0.f,0.f,0.f},{0.f,0.f,0.f,0.f},{0.f,0.f,0.f,0.f}};
        const int sb = arow * A1S;
#pragma unroll
        for (int ks = 0; ks < 4; ks++) {
            short8 a = *(const short8*)&a1s[sb + ks * 32 + grp * 8];
#pragma unroll
            for (int j = 0; j < 3; j++) {
                int o = (n0 + j) * 16 + c;
                short8 b = *(const short8*)&wb2[o * 128 + ks * 32 + grp * 8];
                acc[j] = __builtin_amdgcn_mfma_f32_16x16x32_bf16(a, b, acc[j], 0, 0, 0);
            }
        }
#pragma unroll
        for (int j = 0; j < 3; j++) {
            int o = (n0 + j) * 16 + c;
            float bias = (o < 84) ? f2b[o] : 0.f;
#pragma unroll
            for (int i = 0; i < 4; i++) {
                int s = m * 16 + grp * 4 + i;
                a2s[s * A2S + o] = f2bf(fmaxf(acc[j][i] + bias, 0.f));
            }
        }
    }
    __syncthreads();

    {
        const int n0 = (w >> 1) * 2;
        f32x4 acc[2] = {{0.f,0.f,0.f,0.f},{0.f,0.f,0.f,0.f}};
        const int sb = arow * A2S;
#pragma unroll
        for (int ks = 0; ks < 3; ks++) {
            short8 a = *(const short8*)&a2s[sb + ks * 32 + grp * 8];
#pragma unroll
            for (int j = 0; j < 2; j++) {
                int o = (n0 + j) * 16 + c;
                short8 b = *(const short8*)&wb3[o * 96 + ks * 32 + grp * 8];
                acc[j] = __builtin_amdgcn_mfma_f32_16x16x32_bf16(a, b, acc[j], 0, 0, 0);
            }
        }
#pragma unroll
        for (int j = 0; j < 2; j++) {
            int o = (n0 + j) * 16 + c;
            float bias = f3b[o];
#pragma unroll
            for (int i = 0; i < 4; i++) {
                int s = m * 16 + grp * 4 + i;
                emb[((size_t)blockIdx.x * FCS + s) * 64 + o] = acc[j][i] + bias;
            }
        }
    }
}

__global__ __launch_bounds__(256) void reduce_emb(const float* __restrict__ emb,
                                                  float* __restrict__ part, int total) {
    __shared__ float s_[256];
    const int t = threadIdx.x;
    const int chunk = total / 256;
    const float* base = emb + (size_t)blockIdx.x * chunk;
    float s = 0.f;
    for (int j = t; j < chunk; j += 256) s += base[j];
    s_[t] = s; __syncthreads();
    for (int off = 128; off > 0; off >>= 1) {
        if (t < off) s_[t] += s_[t + off];
        __syncthreads();
    }
    if (t == 0) part[blockIdx.x] = s_[0];
}

__global__ __launch_bounds__(256) void reduce_part(const float* __restrict__ part,
                                                   float* __restrict__ proto) {
    __shared__ float s_[256];
    const int t = threadIdx.x;
    s_[t] = part[t]; __syncthreads();
    for (int off = 128; off > 0; off >>= 1) {
        if (t < off) s_[t] += s_[t + off];
        __syncthreads();
    }
    if (t == 0) proto[0] = s_[0] / 5.0f;
}

__global__ __launch_bounds__(256) void softmax_abs(float* __restrict__ io,
                                                   const float* __restrict__ proto_p) {
    const int lane = threadIdx.x & 63;
    const int row = (blockIdx.x << 2) + (threadIdx.x >> 6);
    const float proto = proto_p[0];
    float e = io[(size_t)row * 64 + lane];
    float m = e;
#pragma unroll
    for (int off = 32; off; off >>= 1) m = fmaxf(m, __shfl_xor(m, off));
    float p = expf(e - m);
    float s = p;
#pragma unroll
    for (int off = 32; off; off >>= 1) s += __shfl_xor(s, off);
    io[(size_t)row * 64 + lane] = fabsf(p / s - proto);
}

extern "C" void kernel_launch(void* const* d_in, const int* in_sizes, int n_in,
                              void* d_out, int out_size, void* d_ws, size_t ws_size,
                              hipStream_t stream) {
    const float* x   = (const float*)d_in[0];
    const float* c1w = (const float*)d_in[1];
    const float* c1b = (const float*)d_in[2];
    const float* c2w = (const float*)d_in[3];
    const float* c2b = (const float*)d_in[4];
    const float* f1w = (const float*)d_in[5];
    const float* f1b = (const float*)d_in[6];
    const float* f2w = (const float*)d_in[7];
    const float* f2b = (const float*)d_in[8];
    const float* f3w = (const float*)d_in[9];
    const float* f3b = (const float*)d_in[10];
    float* out = (float*)d_out;

    const int N = in_sizes[0] / 3072;                 // 20480
    const size_t p1_bytes = (size_t)N * P1_SS * 2;    // 55.4 MB
    const size_t p2_bytes = (size_t)N * 400 * 2;      // 16.4 MB
    unsigned short* P1 = (unsigned short*)d_ws;
    unsigned short* P2 = (unsigned short*)((char*)d_ws + p1_bytes);
    char* tail = (char*)d_ws + p1_bytes + p2_bytes;
    float* part  = (float*)tail;                      // 256 floats
    float* proto = part + 256;                        // 1 float
    unsigned short* wb1  = (unsigned short*)(tail + 2048);  // 128x416
    unsigned short* wb2  = wb1 + 128 * 416;                 // 96x128
    unsigned short* wb3  = wb2 + 96 * 128;                  // 64x96
    unsigned short* c1wf = wb3 + 64 * 96;                   // 10240
    unsigned short* c2wf = c1wf + 10240;                    // 8192

    prep_weights<<<64, 256, 0, stream>>>(c1w, c2w, f1w, f2w, f3w,
                                         wb1, wb2, wb3, c1wf, c2wf);
    conv1_mfma<<<N / 4, 256, 0, stream>>>(x, c1wf, c1b, P1);
    conv2_mfma<<<N / 16, 256, 0, stream>>>(P1, c2wf, c2b, P2);
    fc_mfma<<<N / 32, 256, 0, stream>>>(P2, wb1, f1b, wb2, f2b, wb3, f3b, out);
    reduce_emb<<<256, 256, 0, stream>>>(out, part, N * 64);
    reduce_part<<<1, 256, 0, stream>>>(part, proto);
    softmax_abs<<<N / 4, 256, 0, stream>>>(out, proto);
}